// Round 6
// baseline (103.887 us; speedup 1.0000x reference)
//
#include <hip/hip_runtime.h>

// MockSparseModel: logits[b,t,v] = boost if (mask[b,t]==1 && v==input_ids[b,t]) else 0
// B=8, S=512, V=32768 -> 4096 rows x 32768 fp32 = 512 MiB output, write-BW bound.
//
// R1-R4: four fill shapes all ~5.4 TB/s -> shape-independent limit.
// R5: memset-node + scatter = 90.4 us (fill kernel itself is faster than ours).
// R6 theory: the unified explanation is L2 write-allocate churn — default
// stores allocate dirty lines in the 32 MiB L2, and a 512 MiB stream rides the
// eviction path. Fix: __builtin_nontemporal_store (no-allocate, stream to HBM).
// Fused back into ONE kernel (saves the separate scatter dispatch): each
// float4 written exactly once with the boost element predicated in -> no WAW,
// no ordering hazard with NT stores.

#define VOCAB 32768
#define ROWS  (8 * 512)
#define TPB   256
#define ITERS (VOCAB / (TPB * 4))   // 32 float4-stores per thread per row

typedef float f32x4 __attribute__((ext_vector_type(4)));

__global__ __launch_bounds__(TPB) void mock_sparse_scatter(
    const int* __restrict__ input_ids,
    const int* __restrict__ attention_mask,
    const float* __restrict__ boost_p,
    float* __restrict__ out)
{
    const int row = blockIdx.x;          // 0..4095  (b*S + t), wave-uniform
    const int tid = threadIdx.x;         // 0..255

    // Wave-uniform scalars (s_load).
    const int  id    = input_ids[row];
    const bool valid = (attention_mask[row] == 1) && (id >= 0) && (id < VOCAB);
    const float boost = valid ? boost_p[0] : 0.0f;
    const int  tgt4  = id >> 2;          // target float4 index (uniform)

    f32x4* __restrict__ outr =
        reinterpret_cast<f32x4*>(out + (size_t)row * VOCAB);

    #pragma unroll
    for (int j = 0; j < ITERS; ++j) {
        const int f4i = j * TPB + tid;   // coalesced float4 index in row
        const bool hit = valid && (f4i == tgt4);   // 1 v_cmp per iter
        f32x4 v;
        v.x = (hit && (id & 3) == 0) ? boost : 0.0f;
        v.y = (hit && (id & 3) == 1) ? boost : 0.0f;
        v.z = (hit && (id & 3) == 2) ? boost : 0.0f;
        v.w = (hit && (id & 3) == 3) ? boost : 0.0f;
        __builtin_nontemporal_store(v, &outr[f4i]);  // no L2 allocate, stream
    }
}

extern "C" void kernel_launch(void* const* d_in, const int* in_sizes, int n_in,
                              void* d_out, int out_size, void* d_ws, size_t ws_size,
                              hipStream_t stream) {
    const int*   input_ids      = (const int*)d_in[0];
    const int*   attention_mask = (const int*)d_in[1];
    const float* boost          = (const float*)d_in[2];
    float*       out            = (float*)d_out;

    mock_sparse_scatter<<<ROWS, TPB, 0, stream>>>(input_ids, attention_mask, boost, out);
}

// Round 7
// 90.349 us; speedup vs baseline: 1.1498x; 1.1498x over previous
//
#include <hip/hip_runtime.h>

// MockSparseModel: logits[b,t,v] = boost if (mask[b,t]==1 && v==input_ids[b,t]) else 0
// B=8, S=512, V=32768 -> 4096 rows x 32768 fp32 = 512 MiB output, write-BW bound.
//
// Final structure (best measured, R5 = 90.4 us):
//   1) hipMemsetAsync zero-fill of the full 512 MiB (graph memset node ->
//      rocclr fillBufferAligned, the fastest writer measured on this chip).
//   2) tiny scatter kernel, one thread per (b,t) row, writes the <=4096
//      boosted elements. Stream-ordered after the fill; deterministic.
//
// Post-mortems: fused fills (predicated/pure/phase-rotated/256-block-seq)
// all 98-100 us; NT stores 104 us (L2 write-allocate NOT the limiter).
// Two-point model: steady-state ~7.4 TB/s + ~20 us fixed per-dispatch cost;
// floor for this structure ~85-88 us -> 90.4 is within ~5%.

#define VOCAB 32768
#define ROWS  (8 * 512)

__global__ __launch_bounds__(256) void boost_scatter(
    const int* __restrict__ input_ids,
    const int* __restrict__ attention_mask,
    const float* __restrict__ boost_p,
    float* __restrict__ out)
{
    const int row = blockIdx.x * 256 + threadIdx.x;   // one thread per (b,t)
    if (row >= ROWS) return;
    const int id = input_ids[row];
    if (attention_mask[row] == 1 && id >= 0 && id < VOCAB) {
        out[(size_t)row * VOCAB + id] = boost_p[0];
    }
}

extern "C" void kernel_launch(void* const* d_in, const int* in_sizes, int n_in,
                              void* d_out, int out_size, void* d_ws, size_t ws_size,
                              hipStream_t stream) {
    const int*   input_ids      = (const int*)d_in[0];
    const int*   attention_mask = (const int*)d_in[1];
    const float* boost          = (const float*)d_in[2];
    float*       out            = (float*)d_out;

    // 512 MiB zero-fill via the runtime's fill kernel (graph memset node).
    hipMemsetAsync(out, 0, (size_t)out_size * sizeof(float), stream);

    // Write the <=4096 boosted elements (stream-ordered after the fill).
    boost_scatter<<<ROWS / 256, 256, 0, stream>>>(input_ids, attention_mask, boost, out);
}